// Round 1
// baseline (131.719 us; speedup 1.0000x reference)
//
#include <hip/hip_runtime.h>
#include <hip/hip_bf16.h>
#include <math.h>

// Problem constants (SimpleMemoryBank: B=8,T=4096,D=512,SLOTS=128,TOPK=8)
#define R_TOTAL 32768   // B*T rows
#define DM      512
#define NSLOT   128
#define KSEL    8
#define MTILE   64
#define KTILE   32

__global__ __launch_bounds__(256, 3) void smb_fused(
    const float* __restrict__ q,    // [R_TOTAL, DM]
    const float* __restrict__ Km,   // [NSLOT, DM]
    const float* __restrict__ Vm,   // [NSLOT, DM]
    const float* __restrict__ sal,  // [NSLOT]
    float* __restrict__ outv,       // [R_TOTAL, DM]
    float* __restrict__ outw)       // [R_TOTAL, KSEL]
{
  // LDS: GEMM tiles and the scores buffer are live in disjoint phases -> union.
  __shared__ union U {
    struct { float As[64][36]; float Bs[32][132]; } ab;  // padded strides (bank conflicts)
    float scores[64][132];                               // stride 132: 16B-aligned float4 rows
  } u;
  __shared__ float wbuf[64][KSEL];
  __shared__ int   ibuf[64][KSEL];

  const int t  = threadIdx.x;
  const int r0 = blockIdx.x * MTILE;

  // ---------------- Phase A: scores = q @ K^T (fp32, d-ascending accumulation) -------------
  const int sy    = t >> 5;        // row group 0..7 (8 rows each)
  const int tx    = t & 31;        // slot group (4 slots each)
  const int row_a = t >> 2;        // staging: which row this thread loads
  const int dca   = (t & 3) << 3;  // staging: 8-float column offset

  float sal4[4];
#pragma unroll
  for (int j = 0; j < 4; ++j) sal4[j] = sal[tx * 4 + j];

  float acc[8][4];
#pragma unroll
  for (int i = 0; i < 8; ++i)
#pragma unroll
    for (int j = 0; j < 4; ++j) acc[i][j] = 0.0f;

  for (int dc = 0; dc < DM; dc += KTILE) {
    // global loads for this chunk (issued before the barrier; no LDS touched yet)
    const float4 av0 = *(const float4*)(q + (size_t)(r0 + row_a) * DM + dc + dca);
    const float4 av1 = *(const float4*)(q + (size_t)(r0 + row_a) * DM + dc + dca + 4);
    float4 bv[4];
#pragma unroll
    for (int it = 0; it < 4; ++it) {
      const int uu  = t + it * 256;
      const int s_  = uu >> 3;
      const int dcb = (uu & 7) << 2;
      bv[it] = *(const float4*)(Km + (size_t)s_ * DM + dc + dcb);
    }
    __syncthreads();  // previous chunk's compute done reading LDS
    *(float4*)&u.ab.As[row_a][dca]     = av0;
    *(float4*)&u.ab.As[row_a][dca + 4] = av1;
#pragma unroll
    for (int it = 0; it < 4; ++it) {
      const int uu  = t + it * 256;
      const int s_  = uu >> 3;
      const int dcb = (uu & 7) << 2;
      u.ab.Bs[dcb + 0][s_] = bv[it].x;   // transpose K tile into [d][slot]
      u.ab.Bs[dcb + 1][s_] = bv[it].y;
      u.ab.Bs[dcb + 2][s_] = bv[it].z;
      u.ab.Bs[dcb + 3][s_] = bv[it].w;
    }
    __syncthreads();
#pragma unroll
    for (int d4 = 0; d4 < KTILE; d4 += 4) {
      float a_[8][4], b_[4][4];
#pragma unroll
      for (int i = 0; i < 8; ++i) {
        const float4 v = *(const float4*)&u.ab.As[sy * 8 + i][d4];  // broadcast read
        a_[i][0] = v.x; a_[i][1] = v.y; a_[i][2] = v.z; a_[i][3] = v.w;
      }
#pragma unroll
      for (int dd = 0; dd < 4; ++dd) {
        const float4 v = *(const float4*)&u.ab.Bs[d4 + dd][tx * 4];
        b_[dd][0] = v.x; b_[dd][1] = v.y; b_[dd][2] = v.z; b_[dd][3] = v.w;
      }
      // dd outermost => each acc[i][j] accumulates with d strictly ascending (np-like order)
#pragma unroll
      for (int dd = 0; dd < 4; ++dd)
#pragma unroll
        for (int i = 0; i < 8; ++i)
#pragma unroll
          for (int j = 0; j < 4; ++j)
            acc[i][j] = fmaf(a_[i][dd], b_[dd][j], acc[i][j]);
    }
  }
  __syncthreads();  // done with As/Bs; scores aliases them

  const float den = sqrtf((float)DM);  // 22.627417; IEEE fp32 division below matches np's "/"
#pragma unroll
  for (int i = 0; i < 8; ++i) {
    float4 sc;
    sc.x = acc[i][0] / den + sal4[0];
    sc.y = acc[i][1] / den + sal4[1];
    sc.z = acc[i][2] / den + sal4[2];
    sc.w = acc[i][3] / den + sal4[3];
    *(float4*)&u.scores[sy * 8 + i][tx * 4] = sc;
  }
  __syncthreads();

  // ---------------- Phase B: per-row top-8 (jax.lax.top_k tie semantics) + softmax ---------
  // 4 lanes per row; lane l scans j = 4*jj + l (ascending j within each lane).
  const int row = t >> 2;
  const int l   = t & 3;

  float bs[8]; int bi[8];
#pragma unroll
  for (int p = 0; p < 8; ++p) { bs[p] = -3.0e38f; bi[p] = 0x7fffffff; }

#pragma unroll
  for (int jj = 0; jj < 32; ++jj) {
    const int   j = jj * 4 + l;
    const float s = u.scores[row][j];
    bool c[8];
#pragma unroll
    for (int p = 0; p < 8; ++p) c[p] = s > bs[p];   // strict: equal scores keep earlier index
    float nb[8]; int ni[8];
    nb[0] = c[0] ? s : bs[0];
    ni[0] = c[0] ? j : bi[0];
#pragma unroll
    for (int p = 7; p >= 1; --p) {
      nb[p] = c[p] ? (c[p - 1] ? bs[p - 1] : s) : bs[p];
      ni[p] = c[p] ? (c[p - 1] ? bi[p - 1] : j) : bi[p];
    }
#pragma unroll
    for (int p = 0; p < 8; ++p) { bs[p] = nb[p]; bi[p] = ni[p]; }
  }

  // merge the 4 lanes' sorted lists: 8 rounds of quad-max (score desc, index asc) + pop
  float ts[8]; int ti_[8];
#pragma unroll
  for (int r = 0; r < 8; ++r) {
    float hs = bs[0]; int hi = bi[0];
    {
      const float os = __shfl_xor(hs, 1, 64);
      const int   oi = __shfl_xor(hi, 1, 64);
      if (os > hs || (os == hs && oi < hi)) { hs = os; hi = oi; }
    }
    {
      const float os = __shfl_xor(hs, 2, 64);
      const int   oi = __shfl_xor(hi, 2, 64);
      if (os > hs || (os == hs && oi < hi)) { hs = os; hi = oi; }
    }
    ts[r] = hs; ti_[r] = hi;
    if (bs[0] == hs && bi[0] == hi) {  // winner lane pops its head (static shift)
#pragma unroll
      for (int p = 0; p < 7; ++p) { bs[p] = bs[p + 1]; bi[p] = bi[p + 1]; }
      bs[7] = -3.0e38f; bi[7] = 0x7fffffff;
    }
  }

  // softmax over the 8 selected scores (exp(x - max) / sum), all quad lanes redundantly
  float tw[8];
  const float mx = ts[0];
  float esum = 0.0f;
#pragma unroll
  for (int r = 0; r < 8; ++r) { tw[r] = expf(ts[r] - mx); esum += tw[r]; }
#pragma unroll
  for (int r = 0; r < 8; ++r) tw[r] /= esum;

  if (l == 0) {
#pragma unroll
    for (int r = 0; r < 8; ++r) {
      wbuf[row][r] = tw[r];
      ibuf[row][r] = ti_[r];
      outw[(size_t)(r0 + row) * KSEL + r] = tw[r];
    }
  }
  __syncthreads();

  // ---------------- Phase C: read_vectors = sum_k w_k * V[idx_k] ---------------------------
  // 8 lanes per row; lane o covers float4 columns c = cc*8 + o (128B-coalesced per oct).
  const int o  = t & 7;
  const int rb = t >> 3;  // 0..31
  const float4* __restrict__ V4 = (const float4*)Vm;
  float4* __restrict__ O4 = (float4*)outv;
#pragma unroll
  for (int h = 0; h < 2; ++h) {
    const int rr = rb + h * 32;
    float w8[8]; int i8[8];
#pragma unroll
    for (int r = 0; r < 8; ++r) { w8[r] = wbuf[rr][r]; i8[r] = ibuf[rr][r]; }
    const size_t obase = (size_t)(r0 + rr) * (DM / 4);
#pragma unroll
    for (int cc = 0; cc < 16; ++cc) {
      const int c = cc * 8 + o;
      float4 a; a.x = a.y = a.z = a.w = 0.0f;
#pragma unroll
      for (int r = 0; r < 8; ++r) {  // k ascending, matches reference einsum order
        const float4 v = V4[(size_t)i8[r] * (DM / 4) + c];
        a.x = fmaf(w8[r], v.x, a.x);
        a.y = fmaf(w8[r], v.y, a.y);
        a.z = fmaf(w8[r], v.z, a.z);
        a.w = fmaf(w8[r], v.w, a.w);
      }
      O4[obase + c] = a;
    }
  }
}

extern "C" void kernel_launch(void* const* d_in, const int* in_sizes, int n_in,
                              void* d_out, int out_size, void* d_ws, size_t ws_size,
                              hipStream_t stream) {
  const float* q   = (const float*)d_in[0];
  const float* Km  = (const float*)d_in[1];
  const float* Vm  = (const float*)d_in[2];
  const float* sal = (const float*)d_in[3];
  // d_in[4] is topk (scalar int) — fixed at 8 for this problem.
  float* outv = (float*)d_out;
  float* outw = outv + (size_t)R_TOTAL * DM;  // outputs concatenated flat in return order

  dim3 grid(R_TOTAL / MTILE);
  dim3 block(256);
  hipLaunchKernelGGL(smb_fused, grid, block, 0, stream, q, Km, Vm, sal, outv, outw);
}